// Round 7
// baseline (1549.289 us; speedup 1.0000x reference)
//
#include <hip/hip_runtime.h>

#define NB    8
#define NPTS  16384
#define NS    512
#define NK    64
#define C1    64
#define C2    128
#define RAD2  0.25f
#define MTOT  (NB*NS*NK)   // 262144 rows
// stats layout (floats) in ws after feat:
// [0:64) s0sum | [64:128) s0sq | [128:256) s1sum | [256:384) s1sq
// [384:448) bn0a | [448:512) bn0c | [512:640) bn1a | [640:768) bn1c

typedef float v2f __attribute__((ext_vector_type(2)));

// argmax merge step via DPP move (VALU pipe, no LDS traffic).
#define ARGMAX_DPP(vb, ib, CTRL, RM)                                          \
    do {                                                                      \
        int _mv = __builtin_amdgcn_update_dpp(vb, vb, CTRL, RM, 0xf, false);  \
        int _mi = __builtin_amdgcn_update_dpp(ib, ib, CTRL, RM, 0xf, false);  \
        float _mf = __int_as_float(_mv);                                      \
        float _bf = __int_as_float(vb);                                       \
        bool _t = (_mf > _bf) || (_mf == _bf && _mi < ib);                    \
        vb = _t ? _mv : vb;                                                   \
        ib = _t ? _mi : ib;                                                   \
    } while (0)

// ---------------- FPS: bit-exact farthest point sampling ----------------
// 1024 threads x 16 points as 8 packed pairs. y/z planes in 128 KB dynamic
// LDS as same-coordinate float2 pairs; px + dd packed in VGPRs.
// Distance core in v_pk_add/mul_f32 (bit-exact: a-b == a+(-b), no FMA
// contraction, ((x^2+y^2)+z^2) order). Wave argmax via DPP, block reduce
// lane-parallel, ONE barrier per iteration. launch_bounds(1024,4) -> 128
// VGPR budget so nothing spills (r6 lesson: default budget spilled to AGPR).
__global__ __launch_bounds__(1024, 4) void fps_kernel(const float* __restrict__ xyz,
                                                      float* __restrict__ out) {
    int b = blockIdx.x;
    int tid = threadIdx.x;
    int lane = tid & 63;
    int w = tid >> 6;  // 16 waves
    const float* base = xyz + (size_t)b * NPTS * 3;
    extern __shared__ float lds[];
    v2f* yv = (v2f*)lds;           // [8192] y-pairs (64 KB)
    v2f* zv = yv + 8192;           // [8192] z-pairs (64 KB)
    __shared__ float2 sred[2][16]; // per-wave (value, index-bits), dbuf
    v2f pxp[8], ddp[8];
#pragma unroll
    for (int jj = 0; jj < 8; ++jj) {
        int p0 = tid + (jj << 11);          // j = 2*jj
        int p1 = p0 + 1024;                 // j = 2*jj+1
        float x0 = base[p0 * 3 + 0], y0 = base[p0 * 3 + 1], z0 = base[p0 * 3 + 2];
        float x1 = base[p1 * 3 + 0], y1 = base[p1 * 3 + 1], z1 = base[p1 * 3 + 2];
        pxp[jj][0] = x0; pxp[jj][1] = x1;
        v2f yp; yp[0] = y0; yp[1] = y1;
        v2f zp; zp[0] = z0; zp[1] = z1;
        yv[(jj << 10) + tid] = yp;
        zv[(jj << 10) + tid] = zp;
        ddp[jj][0] = 1e10f; ddp[jj][1] = 1e10f;
    }
    // iteration 0: centroid is point 0
    float cx = base[0], cy = base[1], cz = base[2];
    if (tid == 0) {
        float* o = out + (size_t)b * NS * 3;
        o[0] = cx; o[1] = cy; o[2] = cz;
    }
    __syncthreads();
    for (int i = 1; i < NS; ++i) {
        // exact negation (sign flip): a - c == a + (-c) in IEEE rn
        v2f ncx2; ncx2[0] = -cx; ncx2[1] = -cx;
        v2f ncy2; ncy2[0] = -cy; ncy2[1] = -cy;
        v2f ncz2; ncz2[0] = -cz; ncz2[1] = -cz;
        // 4 independent select chains to break the cmp->cndmask dependency
        float bvA[4] = {-1.f, -1.f, -1.f, -1.f};
        int biA[4] = {0, 0, 0, 0};
#pragma unroll
        for (int jj = 0; jj < 8; ++jj) {
            v2f yp = yv[(jj << 10) + tid];
            v2f zp = zv[(jj << 10) + tid];
            v2f dxp, dyp, dzp, x2, y2, z2, s1, dsq;
            asm("v_pk_add_f32 %0, %1, %2" : "=v"(dxp) : "v"(pxp[jj]), "v"(ncx2));
            asm("v_pk_add_f32 %0, %1, %2" : "=v"(dyp) : "v"(yp), "v"(ncy2));
            asm("v_pk_add_f32 %0, %1, %2" : "=v"(dzp) : "v"(zp), "v"(ncz2));
            asm("v_pk_mul_f32 %0, %1, %1" : "=v"(x2) : "v"(dxp));
            asm("v_pk_mul_f32 %0, %1, %1" : "=v"(y2) : "v"(dyp));
            asm("v_pk_mul_f32 %0, %1, %1" : "=v"(z2) : "v"(dzp));
            asm("v_pk_add_f32 %0, %1, %2" : "=v"(s1) : "v"(x2), "v"(y2));
            asm("v_pk_add_f32 %0, %1, %2" : "=v"(dsq) : "v"(s1), "v"(z2));
            float nd0 = fminf(ddp[jj][0], dsq[0]);
            float nd1 = fminf(ddp[jj][1], dsq[1]);
            ddp[jj][0] = nd0; ddp[jj][1] = nd1;
            int c = jj & 3;
            int p0 = tid + (jj << 11);
            // strict >: earlier j (and lower p) wins within chain
            if (nd0 > bvA[c]) { bvA[c] = nd0; biA[c] = p0; }
            if (nd1 > bvA[c]) { bvA[c] = nd1; biA[c] = p0 + 1024; }
        }
        float bv = bvA[0];
        int bi = biA[0];
#pragma unroll
        for (int c = 1; c < 4; ++c)
            if (bvA[c] > bv || (bvA[c] == bv && biA[c] < bi)) { bv = bvA[c]; bi = biA[c]; }
        int vb = __float_as_int(bv);
        int ib = bi;
        // wave(64) argmax, tie-break min index — all DPP, winner in lane 63
        ARGMAX_DPP(vb, ib, 0xB1, 0xf);   // quad_perm xor1
        ARGMAX_DPP(vb, ib, 0x4E, 0xf);   // quad_perm xor2
        ARGMAX_DPP(vb, ib, 0x141, 0xf);  // row_half_mirror (^7)
        ARGMAX_DPP(vb, ib, 0x140, 0xf);  // row_mirror (^15)
        ARGMAX_DPP(vb, ib, 0x142, 0xa);  // row_bcast15 -> rows 1,3
        ARGMAX_DPP(vb, ib, 0x143, 0xc);  // row_bcast31 -> rows 2,3
        float wv = __int_as_float(__builtin_amdgcn_readlane(vb, 63));
        int wi = __builtin_amdgcn_readlane(ib, 63);
        if (lane == 0) sred[i & 1][w] = make_float2(wv, __int_as_float(wi));
        __syncthreads();
        // block reduce: lanes read sred[lane&15] (16-groups identical),
        // 4 within-row DPP steps -> every lane holds the block winner
        float2 c2 = sred[i & 1][lane & 15];
        int vb2 = __float_as_int(c2.x);
        int ib2 = __float_as_int(c2.y);
        ARGMAX_DPP(vb2, ib2, 0xB1, 0xf);
        ARGMAX_DPP(vb2, ib2, 0x4E, 0xf);
        ARGMAX_DPP(vb2, ib2, 0x141, 0xf);
        ARGMAX_DPP(vb2, ib2, 0x140, 0xf);
        int ii = __builtin_amdgcn_readfirstlane(ib2);  // uniform winner index
        const float* cp = base + (size_t)ii * 3;
        cx = cp[0]; cy = cp[1]; cz = cp[2];
        if (tid == 0) {
            float* o = out + ((size_t)b * NS + i) * 3;
            o[0] = cx; o[1] = cy; o[2] = cz;
        }
    }
}

// ------------- Ball query (exact expanded-form distance) + gather -------------
__global__ __launch_bounds__(256) void ballq_kernel(const float* __restrict__ xyz,
                                                    const float* __restrict__ pts,
                                                    const float* __restrict__ newxyz,
                                                    float* __restrict__ feat) {
    int w = threadIdx.x >> 6;
    int lane = threadIdx.x & 63;
    int wid = blockIdx.x * 4 + w;   // 0..4095 == b*512+s
    int b = wid >> 9;
    const float* nx = newxyz + (size_t)wid * 3;
    float cx = nx[0], cy = nx[1], cz = nx[2];
    float sa = __fadd_rn(__fadd_rn(__fmul_rn(cx, cx), __fmul_rn(cy, cy)),
                         __fmul_rn(cz, cz));
    __shared__ int sidx[4][64];
    const float* base = xyz + (size_t)b * NPTS * 3;
    int cnt = 0;
    for (int off = 0; off < NPTS && cnt < NK; off += 64) {
        int p = off + lane;
        float bx = base[p * 3 + 0], by = base[p * 3 + 1], bz = base[p * 3 + 2];
        float sb = __fadd_rn(__fadd_rn(__fmul_rn(bx, bx), __fmul_rn(by, by)),
                             __fmul_rn(bz, bz));
        float dt = __fadd_rn(__fadd_rn(__fmul_rn(cx, bx), __fmul_rn(cy, by)),
                             __fmul_rn(cz, bz));
        float sq = __fsub_rn(__fadd_rn(sa, sb), __fmul_rn(2.0f, dt));
        bool inb = !(sq > RAD2);           // strict >, matches reference
        unsigned long long mask = __ballot(inb);
        int pos = cnt + (int)__popcll(mask & ((1ull << lane) - 1ull));
        if (inb && pos < NK) sidx[w][pos] = p;
        cnt += (int)__popcll(mask);
    }
    __syncthreads();
    int filled = cnt < NK ? cnt : NK;
    int sel = (lane < filled) ? lane : 0;
    int p = (filled > 0) ? sidx[w][sel] : 0;  // filled>0 always (self in radius)
    float gx = base[p * 3 + 0], gy = base[p * 3 + 1], gz = base[p * 3 + 2];
    const float* pb = pts + (size_t)b * NPTS * 3;
    float q0 = pb[p * 3 + 0], q1 = pb[p * 3 + 1], q2 = pb[p * 3 + 2];
    float* fr = feat + ((size_t)wid * NK + lane) * 6;
    fr[0] = __fsub_rn(gx, cx);
    fr[1] = __fsub_rn(gy, cy);
    fr[2] = __fsub_rn(gz, cz);
    fr[3] = q0; fr[4] = q1; fr[5] = q2;
}

// ---------------- Layer-0 stats: per-channel sum/sumsq of h0raw ----------------
__global__ __launch_bounds__(256) void stats0_kernel(const float* __restrict__ feat,
                                                     const float* __restrict__ W0,
                                                     const float* __restrict__ b0,
                                                     float* __restrict__ stats) {
    int lane = threadIdx.x & 63;
    int wid = blockIdx.x * 4 + (threadIdx.x >> 6);  // 0..1023
    float w0[6];
#pragma unroll
    for (int j = 0; j < 6; ++j) w0[j] = W0[lane * 6 + j];
    float bb = b0[lane];
    float ssum = 0.f, ssq = 0.f;
    int r0 = wid * 256;
    for (int r = r0; r < r0 + 256; ++r) {
        const float* f = feat + (size_t)r * 6;
        float h = bb;
#pragma unroll
        for (int j = 0; j < 6; ++j) h = fmaf(w0[j], f[j], h);
        ssum += h;
        ssq = fmaf(h, h, ssq);
    }
    atomicAdd(&stats[lane], ssum);
    atomicAdd(&stats[64 + lane], ssq);
}

__global__ void fin0_kernel(const float* __restrict__ g0, const float* __restrict__ be0,
                            float* __restrict__ stats) {
    int c = threadIdx.x;  // 64 threads
    const float inv = 1.0f / (float)MTOT;  // 2^-18, exact
    float mu = stats[c] * inv;
    float var = fmaxf(stats[64 + c] * inv - mu * mu, 0.f);
    float a = g0[c] * rsqrtf(var + 1e-5f);
    stats[384 + c] = a;
    stats[448 + c] = fmaf(-mu, a, be0[c]);
}

// ---------------- Layer-1 stats: recompute h0n -> h1raw, sum/sumsq ----------------
__global__ __launch_bounds__(256) void stats1_kernel(const float* __restrict__ feat,
                                                     const float* __restrict__ W0,
                                                     const float* __restrict__ b0,
                                                     const float* __restrict__ W1,
                                                     const float* __restrict__ b1,
                                                     float* __restrict__ stats) {
    int lane = threadIdx.x & 63;
    int w = threadIdx.x >> 6;
    int half = w & 1;
    int pairG = blockIdx.x * 2 + (w >> 1);  // 0..2047
    int ch = half * 64 + lane;
    float w0r[6];
#pragma unroll
    for (int j = 0; j < 6; ++j) w0r[j] = W0[lane * 6 + j];
    float b0v = b0[lane];
    float a0 = stats[384 + lane], c0 = stats[448 + lane];
    float w1r[64];
#pragma unroll
    for (int j = 0; j < 64; ++j) w1r[j] = W1[ch * 64 + j];
    float b1v = b1[ch];
    float ssum = 0.f, ssq = 0.f;
    int r0 = pairG * 128;
    for (int r = r0; r < r0 + 128; ++r) {
        const float* f = feat + (size_t)r * 6;
        float h = b0v;
#pragma unroll
        for (int j = 0; j < 6; ++j) h = fmaf(w0r[j], f[j], h);
        float h0n = fmaxf(fmaf(a0, h, c0), 0.f);
        int hbits = __float_as_int(h0n);
        float a0c = 0.f, a1c = 0.f, a2c = 0.f, a3c = 0.f;
#pragma unroll
        for (int j = 0; j < 64; j += 4) {
            a0c = fmaf(w1r[j + 0], __int_as_float(__builtin_amdgcn_readlane(hbits, j + 0)), a0c);
            a1c = fmaf(w1r[j + 1], __int_as_float(__builtin_amdgcn_readlane(hbits, j + 1)), a1c);
            a2c = fmaf(w1r[j + 2], __int_as_float(__builtin_amdgcn_readlane(hbits, j + 2)), a2c);
            a3c = fmaf(w1r[j + 3], __int_as_float(__builtin_amdgcn_readlane(hbits, j + 3)), a3c);
        }
        float acc = b1v + ((a0c + a1c) + (a2c + a3c));
        ssum += acc;
        ssq = fmaf(acc, acc, ssq);
    }
    atomicAdd(&stats[128 + ch], ssum);
    atomicAdd(&stats[256 + ch], ssq);
}

__global__ void fin1_kernel(const float* __restrict__ g1, const float* __restrict__ be1,
                            float* __restrict__ stats) {
    int c = threadIdx.x;  // 128 threads
    const float inv = 1.0f / (float)MTOT;
    float mu = stats[128 + c] * inv;
    float var = fmaxf(stats[256 + c] * inv - mu * mu, 0.f);
    float a = g1[c] * rsqrtf(var + 1e-5f);
    stats[512 + c] = a;
    stats[640 + c] = fmaf(-mu, a, be1[c]);
}

// ---------------- Final: recompute h1n, max over K, write output ----------------
__global__ __launch_bounds__(256) void final_kernel(const float* __restrict__ feat,
                                                    const float* __restrict__ W0,
                                                    const float* __restrict__ b0,
                                                    const float* __restrict__ W1,
                                                    const float* __restrict__ b1,
                                                    const float* __restrict__ stats,
                                                    float* __restrict__ out) {
    int lane = threadIdx.x & 63;
    int w = threadIdx.x >> 6;
    int half = w & 1;
    int g = blockIdx.x * 2 + (w >> 1);  // 0..4095 == b*512+s
    int ch = half * 64 + lane;
    float w0r[6];
#pragma unroll
    for (int j = 0; j < 6; ++j) w0r[j] = W0[lane * 6 + j];
    float b0v = b0[lane];
    float a0 = stats[384 + lane], c0 = stats[448 + lane];
    float w1r[64];
#pragma unroll
    for (int j = 0; j < 64; ++j) w1r[j] = W1[ch * 64 + j];
    float b1v = b1[ch];
    float a1 = stats[512 + ch], c1 = stats[640 + ch];
    float mx = -1e30f;
    int r0 = g * 64;
    for (int k = 0; k < 64; ++k) {
        const float* f = feat + (size_t)(r0 + k) * 6;
        float h = b0v;
#pragma unroll
        for (int j = 0; j < 6; ++j) h = fmaf(w0r[j], f[j], h);
        float h0n = fmaxf(fmaf(a0, h, c0), 0.f);
        int hbits = __float_as_int(h0n);
        float a0c = 0.f, a1c = 0.f, a2c = 0.f, a3c = 0.f;
#pragma unroll
        for (int j = 0; j < 64; j += 4) {
            a0c = fmaf(w1r[j + 0], __int_as_float(__builtin_amdgcn_readlane(hbits, j + 0)), a0c);
            a1c = fmaf(w1r[j + 1], __int_as_float(__builtin_amdgcn_readlane(hbits, j + 1)), a1c);
            a2c = fmaf(w1r[j + 2], __int_as_float(__builtin_amdgcn_readlane(hbits, j + 2)), a2c);
            a3c = fmaf(w1r[j + 3], __int_as_float(__builtin_amdgcn_readlane(hbits, j + 3)), a3c);
        }
        float acc = b1v + ((a0c + a1c) + (a2c + a3c));
        float h1n = fmaxf(fmaf(a1, acc, c1), 0.f);
        mx = fmaxf(mx, h1n);
    }
    out[12288 + (size_t)g * 128 + ch] = mx;
}

extern "C" void kernel_launch(void* const* d_in, const int* in_sizes, int n_in,
                              void* d_out, int out_size, void* d_ws, size_t ws_size,
                              hipStream_t stream) {
    const float* xyz = (const float*)d_in[0];
    const float* pts = (const float*)d_in[1];
    const float* W0  = (const float*)d_in[2];
    const float* b0  = (const float*)d_in[3];
    const float* g0  = (const float*)d_in[4];
    const float* be0 = (const float*)d_in[5];
    const float* W1  = (const float*)d_in[6];
    const float* b1  = (const float*)d_in[7];
    const float* g1  = (const float*)d_in[8];
    const float* be1 = (const float*)d_in[9];
    float* out = (float*)d_out;

    float* feat  = (float*)d_ws;                     // 262144*6 floats = 6.29 MB
    float* stats = feat + (size_t)MTOT * 6;          // 768 floats

    // opt-in to 128 KB dynamic LDS for fps (idempotent, host-side, capture-safe)
    const int fps_lds = 2 * NPTS * (int)sizeof(float);  // 131072
    hipFuncSetAttribute(reinterpret_cast<const void*>(fps_kernel),
                        hipFuncAttributeMaxDynamicSharedMemorySize, fps_lds);

    hipMemsetAsync(stats, 0, 384 * sizeof(float), stream);
    fps_kernel<<<NB, 1024, fps_lds, stream>>>(xyz, out);
    ballq_kernel<<<1024, 256, 0, stream>>>(xyz, pts, out, feat);
    stats0_kernel<<<256, 256, 0, stream>>>(feat, W0, b0, stats);
    fin0_kernel<<<1, 64, 0, stream>>>(g0, be0, stats);
    stats1_kernel<<<1024, 256, 0, stream>>>(feat, W0, b0, W1, b1, stats);
    fin1_kernel<<<1, 128, 0, stream>>>(g1, be1, stats);
    final_kernel<<<2048, 256, 0, stream>>>(feat, W0, b0, W1, b1, stats, out);
}

// Round 8
// 1218.883 us; speedup vs baseline: 1.2711x; 1.2711x over previous
//
#include <hip/hip_runtime.h>

#define NB    8
#define NPTS  16384
#define NS    512
#define NK    64
#define C1    64
#define C2    128
#define RAD2  0.25f
#define MTOT  (NB*NS*NK)   // 262144 rows
// stats layout (floats) in ws after feat:
// [0:64) s0sum | [64:128) s0sq | [128:256) s1sum | [256:384) s1sq
// [384:448) bn0a | [448:512) bn0c | [512:640) bn1a | [640:768) bn1c

typedef float v2f __attribute__((ext_vector_type(2)));

// u32 max/min reduce steps via DPP (positive floats compare as u32).
// update_dpp(old=x, src=x): masked-out rows keep x -> self-compare no-op.
#define UMAX_DPP(x, CTRL, RM)                                                   \
    do {                                                                        \
        unsigned _m = (unsigned)__builtin_amdgcn_update_dpp((int)(x), (int)(x), \
                                                            CTRL, RM, 0xf, false); \
        x = (x > _m) ? x : _m;                                                  \
    } while (0)
#define UMIN_DPP(x, CTRL, RM)                                                   \
    do {                                                                        \
        unsigned _m = (unsigned)__builtin_amdgcn_update_dpp((int)(x), (int)(x), \
                                                            CTRL, RM, 0xf, false); \
        x = (x < _m) ? x : _m;                                                  \
    } while (0)

// ---------------- FPS: bit-exact farthest point sampling ----------------
// 1024 threads x 16 points (8 float2 pairs). y/z planes in 128 KB dynamic
// LDS; px + dd in VGPRs (~48 regs, fits default budget -> no spill fight).
// VALUE-ONLY scan (plain float2 ops, fp contract off -> bit-exact, compiler
// schedules freely, no inline asm); wave+block u32-max reduce gives exact
// block max W; index discovered once per block by the wave(s) holding W
// (lowest flat index == jnp.argmax semantics); 2 barriers/iter.
__global__ __launch_bounds__(1024, 4) void fps_kernel(const float* __restrict__ xyz,
                                                      float* __restrict__ out) {
#pragma clang fp contract(off)
    int b = blockIdx.x;
    int tid = threadIdx.x;
    int lane = tid & 63;
    int w = tid >> 6;  // 16 waves
    const float* base = xyz + (size_t)b * NPTS * 3;
    extern __shared__ float lds[];
    v2f* yv = (v2f*)lds;           // [8192] y-pairs (64 KB)
    v2f* zv = yv + 8192;           // [8192] z-pairs (64 KB)
    __shared__ unsigned svals[2][16];  // per-wave max value bits, dbuf
    __shared__ unsigned sidxs[2][16];  // per-wave min candidate idx, dbuf
    v2f pxp[8], ddp[8];
#pragma unroll
    for (int jj = 0; jj < 8; ++jj) {
        int p0 = tid + (jj << 11);          // pair: (p0, p0+1024)
        int p1 = p0 + 1024;
        float x0 = base[p0 * 3 + 0], y0 = base[p0 * 3 + 1], z0 = base[p0 * 3 + 2];
        float x1 = base[p1 * 3 + 0], y1 = base[p1 * 3 + 1], z1 = base[p1 * 3 + 2];
        pxp[jj].x = x0; pxp[jj].y = x1;
        v2f yp; yp.x = y0; yp.y = y1;
        v2f zp; zp.x = z0; zp.y = z1;
        yv[(jj << 10) + tid] = yp;
        zv[(jj << 10) + tid] = zp;
        ddp[jj].x = 1e10f; ddp[jj].y = 1e10f;
    }
    // iteration 0: centroid is point 0
    float cx = base[0], cy = base[1], cz = base[2];
    if (tid == 0) {
        float* o = out + (size_t)b * NS * 3;
        o[0] = cx; o[1] = cy; o[2] = cz;
    }
    __syncthreads();
    for (int i = 1; i < NS; ++i) {
        v2f cx2; cx2.x = cx; cx2.y = cx;
        v2f cy2; cy2.x = cy; cy2.y = cy;
        v2f cz2; cz2.x = cz; cz2.y = cz;
        // value-only scan; 4 independent packed max chains
        v2f cm0, cm1, cm2, cm3;
        cm0.x = -1.f; cm0.y = -1.f; cm1 = cm0; cm2 = cm0; cm3 = cm0;
#pragma unroll
        for (int jj = 0; jj < 8; ++jj) {
            v2f yp = yv[(jj << 10) + tid];
            v2f zp = zv[(jj << 10) + tid];
            // bit-exact: contract(off) -> separate rn mul/add, order ((x2+y2)+z2)
            v2f dx = pxp[jj] - cx2;
            v2f dy = yp - cy2;
            v2f dz = zp - cz2;
            v2f d = (dx * dx + dy * dy) + dz * dz;
            v2f nd;
            nd.x = fminf(ddp[jj].x, d.x);
            nd.y = fminf(ddp[jj].y, d.y);
            ddp[jj] = nd;
            if ((jj & 3) == 0) { cm0.x = fmaxf(cm0.x, nd.x); cm0.y = fmaxf(cm0.y, nd.y); }
            if ((jj & 3) == 1) { cm1.x = fmaxf(cm1.x, nd.x); cm1.y = fmaxf(cm1.y, nd.y); }
            if ((jj & 3) == 2) { cm2.x = fmaxf(cm2.x, nd.x); cm2.y = fmaxf(cm2.y, nd.y); }
            if ((jj & 3) == 3) { cm3.x = fmaxf(cm3.x, nd.x); cm3.y = fmaxf(cm3.y, nd.y); }
        }
        v2f m01; m01.x = fmaxf(cm0.x, cm1.x); m01.y = fmaxf(cm0.y, cm1.y);
        v2f m23; m23.x = fmaxf(cm2.x, cm3.x); m23.y = fmaxf(cm2.y, cm3.y);
        float bv = fmaxf(fmaxf(m01.x, m23.x), fmaxf(m01.y, m23.y));  // thread max (exact)
        // wave(64) value max via DPP on u32 bits (positive floats)
        unsigned vb = (unsigned)__float_as_int(bv);
        UMAX_DPP(vb, 0xB1, 0xf);   // quad_perm xor1
        UMAX_DPP(vb, 0x4E, 0xf);   // quad_perm xor2
        UMAX_DPP(vb, 0x141, 0xf);  // row_half_mirror
        UMAX_DPP(vb, 0x140, 0xf);  // row_mirror
        UMAX_DPP(vb, 0x142, 0xa);  // row_bcast15
        UMAX_DPP(vb, 0x143, 0xc);  // row_bcast31
        if (lane == 63) svals[i & 1][w] = vb;
        __syncthreads();           // barrier 1: wave maxes visible
        // block value max: all lanes reduce the 16 slots
        unsigned wv = svals[i & 1][lane & 15];
        UMAX_DPP(wv, 0xB1, 0xf);
        UMAX_DPP(wv, 0x4E, 0xf);
        UMAX_DPP(wv, 0x141, 0xf);
        UMAX_DPP(wv, 0x140, 0xf);
        float W = __int_as_float((int)wv);  // exact block max, uniform
        // index discovery: only wave(s) holding W scan their registers
        unsigned lidx = 0x7fffffffu;
        if (__any(bv == W)) {
#pragma unroll
            for (int jj = 7; jj >= 0; --jj) {  // descending -> lowest idx wins
                if (ddp[jj].y == W) lidx = (unsigned)(tid + (jj << 11) + 1024);
                if (ddp[jj].x == W) lidx = (unsigned)(tid + (jj << 11));
            }
        }
        UMIN_DPP(lidx, 0xB1, 0xf);
        UMIN_DPP(lidx, 0x4E, 0xf);
        UMIN_DPP(lidx, 0x141, 0xf);
        UMIN_DPP(lidx, 0x140, 0xf);
        UMIN_DPP(lidx, 0x142, 0xa);
        UMIN_DPP(lidx, 0x143, 0xc);
        if (lane == 63) sidxs[i & 1][w] = lidx;
        __syncthreads();           // barrier 2: candidate indices visible
        unsigned ci = sidxs[i & 1][lane & 15];
        UMIN_DPP(ci, 0xB1, 0xf);
        UMIN_DPP(ci, 0x4E, 0xf);
        UMIN_DPP(ci, 0x141, 0xf);
        UMIN_DPP(ci, 0x140, 0xf);
        int ii = __builtin_amdgcn_readfirstlane((int)ci);  // uniform winner
        const float* cp = base + (size_t)ii * 3;
        cx = cp[0]; cy = cp[1]; cz = cp[2];
        if (tid == 0) {
            float* o = out + ((size_t)b * NS + i) * 3;
            o[0] = cx; o[1] = cy; o[2] = cz;
        }
    }
}

// ------------- Ball query (exact expanded-form distance) + gather -------------
__global__ __launch_bounds__(256) void ballq_kernel(const float* __restrict__ xyz,
                                                    const float* __restrict__ pts,
                                                    const float* __restrict__ newxyz,
                                                    float* __restrict__ feat) {
    int w = threadIdx.x >> 6;
    int lane = threadIdx.x & 63;
    int wid = blockIdx.x * 4 + w;   // 0..4095 == b*512+s
    int b = wid >> 9;
    const float* nx = newxyz + (size_t)wid * 3;
    float cx = nx[0], cy = nx[1], cz = nx[2];
    float sa = __fadd_rn(__fadd_rn(__fmul_rn(cx, cx), __fmul_rn(cy, cy)),
                         __fmul_rn(cz, cz));
    __shared__ int sidx[4][64];
    const float* base = xyz + (size_t)b * NPTS * 3;
    int cnt = 0;
    for (int off = 0; off < NPTS && cnt < NK; off += 64) {
        int p = off + lane;
        float bx = base[p * 3 + 0], by = base[p * 3 + 1], bz = base[p * 3 + 2];
        float sb = __fadd_rn(__fadd_rn(__fmul_rn(bx, bx), __fmul_rn(by, by)),
                             __fmul_rn(bz, bz));
        float dt = __fadd_rn(__fadd_rn(__fmul_rn(cx, bx), __fmul_rn(cy, by)),
                             __fmul_rn(cz, bz));
        float sq = __fsub_rn(__fadd_rn(sa, sb), __fmul_rn(2.0f, dt));
        bool inb = !(sq > RAD2);           // strict >, matches reference
        unsigned long long mask = __ballot(inb);
        int pos = cnt + (int)__popcll(mask & ((1ull << lane) - 1ull));
        if (inb && pos < NK) sidx[w][pos] = p;
        cnt += (int)__popcll(mask);
    }
    __syncthreads();
    int filled = cnt < NK ? cnt : NK;
    int sel = (lane < filled) ? lane : 0;
    int p = (filled > 0) ? sidx[w][sel] : 0;  // filled>0 always (self in radius)
    float gx = base[p * 3 + 0], gy = base[p * 3 + 1], gz = base[p * 3 + 2];
    const float* pb = pts + (size_t)b * NPTS * 3;
    float q0 = pb[p * 3 + 0], q1 = pb[p * 3 + 1], q2 = pb[p * 3 + 2];
    float* fr = feat + ((size_t)wid * NK + lane) * 6;
    fr[0] = __fsub_rn(gx, cx);
    fr[1] = __fsub_rn(gy, cy);
    fr[2] = __fsub_rn(gz, cz);
    fr[3] = q0; fr[4] = q1; fr[5] = q2;
}

// ---------------- Layer-0 stats: per-channel sum/sumsq of h0raw ----------------
__global__ __launch_bounds__(256) void stats0_kernel(const float* __restrict__ feat,
                                                     const float* __restrict__ W0,
                                                     const float* __restrict__ b0,
                                                     float* __restrict__ stats) {
    int lane = threadIdx.x & 63;
    int wid = blockIdx.x * 4 + (threadIdx.x >> 6);  // 0..1023
    float w0[6];
#pragma unroll
    for (int j = 0; j < 6; ++j) w0[j] = W0[lane * 6 + j];
    float bb = b0[lane];
    float ssum = 0.f, ssq = 0.f;
    int r0 = wid * 256;
    for (int r = r0; r < r0 + 256; ++r) {
        const float* f = feat + (size_t)r * 6;
        float h = bb;
#pragma unroll
        for (int j = 0; j < 6; ++j) h = fmaf(w0[j], f[j], h);
        ssum += h;
        ssq = fmaf(h, h, ssq);
    }
    atomicAdd(&stats[lane], ssum);
    atomicAdd(&stats[64 + lane], ssq);
}

__global__ void fin0_kernel(const float* __restrict__ g0, const float* __restrict__ be0,
                            float* __restrict__ stats) {
    int c = threadIdx.x;  // 64 threads
    const float inv = 1.0f / (float)MTOT;  // 2^-18, exact
    float mu = stats[c] * inv;
    float var = fmaxf(stats[64 + c] * inv - mu * mu, 0.f);
    float a = g0[c] * rsqrtf(var + 1e-5f);
    stats[384 + c] = a;
    stats[448 + c] = fmaf(-mu, a, be0[c]);
}

// ---------------- Layer-1 stats: recompute h0n -> h1raw, sum/sumsq ----------------
__global__ __launch_bounds__(256) void stats1_kernel(const float* __restrict__ feat,
                                                     const float* __restrict__ W0,
                                                     const float* __restrict__ b0,
                                                     const float* __restrict__ W1,
                                                     const float* __restrict__ b1,
                                                     float* __restrict__ stats) {
    int lane = threadIdx.x & 63;
    int w = threadIdx.x >> 6;
    int half = w & 1;
    int pairG = blockIdx.x * 2 + (w >> 1);  // 0..2047
    int ch = half * 64 + lane;
    float w0r[6];
#pragma unroll
    for (int j = 0; j < 6; ++j) w0r[j] = W0[lane * 6 + j];
    float b0v = b0[lane];
    float a0 = stats[384 + lane], c0 = stats[448 + lane];
    float w1r[64];
#pragma unroll
    for (int j = 0; j < 64; ++j) w1r[j] = W1[ch * 64 + j];
    float b1v = b1[ch];
    float ssum = 0.f, ssq = 0.f;
    int r0 = pairG * 128;
    for (int r = r0; r < r0 + 128; ++r) {
        const float* f = feat + (size_t)r * 6;
        float h = b0v;
#pragma unroll
        for (int j = 0; j < 6; ++j) h = fmaf(w0r[j], f[j], h);
        float h0n = fmaxf(fmaf(a0, h, c0), 0.f);
        int hbits = __float_as_int(h0n);
        float a0c = 0.f, a1c = 0.f, a2c = 0.f, a3c = 0.f;
#pragma unroll
        for (int j = 0; j < 64; j += 4) {
            a0c = fmaf(w1r[j + 0], __int_as_float(__builtin_amdgcn_readlane(hbits, j + 0)), a0c);
            a1c = fmaf(w1r[j + 1], __int_as_float(__builtin_amdgcn_readlane(hbits, j + 1)), a1c);
            a2c = fmaf(w1r[j + 2], __int_as_float(__builtin_amdgcn_readlane(hbits, j + 2)), a2c);
            a3c = fmaf(w1r[j + 3], __int_as_float(__builtin_amdgcn_readlane(hbits, j + 3)), a3c);
        }
        float acc = b1v + ((a0c + a1c) + (a2c + a3c));
        ssum += acc;
        ssq = fmaf(acc, acc, ssq);
    }
    atomicAdd(&stats[128 + ch], ssum);
    atomicAdd(&stats[256 + ch], ssq);
}

__global__ void fin1_kernel(const float* __restrict__ g1, const float* __restrict__ be1,
                            float* __restrict__ stats) {
    int c = threadIdx.x;  // 128 threads
    const float inv = 1.0f / (float)MTOT;
    float mu = stats[128 + c] * inv;
    float var = fmaxf(stats[256 + c] * inv - mu * mu, 0.f);
    float a = g1[c] * rsqrtf(var + 1e-5f);
    stats[512 + c] = a;
    stats[640 + c] = fmaf(-mu, a, be1[c]);
}

// ---------------- Final: recompute h1n, max over K, write output ----------------
__global__ __launch_bounds__(256) void final_kernel(const float* __restrict__ feat,
                                                    const float* __restrict__ W0,
                                                    const float* __restrict__ b0,
                                                    const float* __restrict__ W1,
                                                    const float* __restrict__ b1,
                                                    const float* __restrict__ stats,
                                                    float* __restrict__ out) {
    int lane = threadIdx.x & 63;
    int w = threadIdx.x >> 6;
    int half = w & 1;
    int g = blockIdx.x * 2 + (w >> 1);  // 0..4095 == b*512+s
    int ch = half * 64 + lane;
    float w0r[6];
#pragma unroll
    for (int j = 0; j < 6; ++j) w0r[j] = W0[lane * 6 + j];
    float b0v = b0[lane];
    float a0 = stats[384 + lane], c0 = stats[448 + lane];
    float w1r[64];
#pragma unroll
    for (int j = 0; j < 64; ++j) w1r[j] = W1[ch * 64 + j];
    float b1v = b1[ch];
    float a1 = stats[512 + ch], c1 = stats[640 + ch];
    float mx = -1e30f;
    int r0 = g * 64;
    for (int k = 0; k < 64; ++k) {
        const float* f = feat + (size_t)(r0 + k) * 6;
        float h = b0v;
#pragma unroll
        for (int j = 0; j < 6; ++j) h = fmaf(w0r[j], f[j], h);
        float h0n = fmaxf(fmaf(a0, h, c0), 0.f);
        int hbits = __float_as_int(h0n);
        float a0c = 0.f, a1c = 0.f, a2c = 0.f, a3c = 0.f;
#pragma unroll
        for (int j = 0; j < 64; j += 4) {
            a0c = fmaf(w1r[j + 0], __int_as_float(__builtin_amdgcn_readlane(hbits, j + 0)), a0c);
            a1c = fmaf(w1r[j + 1], __int_as_float(__builtin_amdgcn_readlane(hbits, j + 1)), a1c);
            a2c = fmaf(w1r[j + 2], __int_as_float(__builtin_amdgcn_readlane(hbits, j + 2)), a2c);
            a3c = fmaf(w1r[j + 3], __int_as_float(__builtin_amdgcn_readlane(hbits, j + 3)), a3c);
        }
        float acc = b1v + ((a0c + a1c) + (a2c + a3c));
        float h1n = fmaxf(fmaf(a1, acc, c1), 0.f);
        mx = fmaxf(mx, h1n);
    }
    out[12288 + (size_t)g * 128 + ch] = mx;
}

extern "C" void kernel_launch(void* const* d_in, const int* in_sizes, int n_in,
                              void* d_out, int out_size, void* d_ws, size_t ws_size,
                              hipStream_t stream) {
    const float* xyz = (const float*)d_in[0];
    const float* pts = (const float*)d_in[1];
    const float* W0  = (const float*)d_in[2];
    const float* b0  = (const float*)d_in[3];
    const float* g0  = (const float*)d_in[4];
    const float* be0 = (const float*)d_in[5];
    const float* W1  = (const float*)d_in[6];
    const float* b1  = (const float*)d_in[7];
    const float* g1  = (const float*)d_in[8];
    const float* be1 = (const float*)d_in[9];
    float* out = (float*)d_out;

    float* feat  = (float*)d_ws;                     // 262144*6 floats = 6.29 MB
    float* stats = feat + (size_t)MTOT * 6;          // 768 floats

    // opt-in to 128 KB dynamic LDS for fps (idempotent, host-side, capture-safe)
    const int fps_lds = 2 * NPTS * (int)sizeof(float);  // 131072
    hipFuncSetAttribute(reinterpret_cast<const void*>(fps_kernel),
                        hipFuncAttributeMaxDynamicSharedMemorySize, fps_lds);

    hipMemsetAsync(stats, 0, 384 * sizeof(float), stream);
    fps_kernel<<<NB, 1024, fps_lds, stream>>>(xyz, out);
    ballq_kernel<<<1024, 256, 0, stream>>>(xyz, pts, out, feat);
    stats0_kernel<<<256, 256, 0, stream>>>(feat, W0, b0, stats);
    fin0_kernel<<<1, 64, 0, stream>>>(g0, be0, stats);
    stats1_kernel<<<1024, 256, 0, stream>>>(feat, W0, b0, W1, b1, stats);
    fin1_kernel<<<1, 128, 0, stream>>>(g1, be1, stats);
    final_kernel<<<2048, 256, 0, stream>>>(feat, W0, b0, W1, b1, stats, out);
}

// Round 11
// 1159.598 us; speedup vs baseline: 1.3361x; 1.0511x over previous
//
#include <hip/hip_runtime.h>

#define NB    8
#define NPTS  16384
#define NS    512
#define NK    64
#define C1    64
#define C2    128
#define RAD2  0.25f
#define MTOT  (NB*NS*NK)   // 262144 rows
// stats layout (floats) in ws after feat:
// [0:64) s0sum | [64:128) s0sq | [128:256) s1sum | [256:384) s1sq
// [384:448) bn0a | [448:512) bn0c | [512:640) bn1a | [640:768) bn1c

typedef float v2f __attribute__((ext_vector_type(2)));
typedef __bf16 bfv8 __attribute__((ext_vector_type(8)));   // MFMA A/B fragment (V8y)
typedef float f32x4 __attribute__((ext_vector_type(4)));

extern __shared__ char dynsmem[];   // single TU-wide dynamic-LDS symbol

// u32 max/min reduce steps via DPP (positive floats compare as u32).
#define UMAX_DPP(x, CTRL, RM)                                                   \
    do {                                                                        \
        unsigned _m = (unsigned)__builtin_amdgcn_update_dpp((int)(x), (int)(x), \
                                                            CTRL, RM, 0xf, false); \
        x = (x > _m) ? x : _m;                                                  \
    } while (0)
#define UMIN_DPP(x, CTRL, RM)                                                   \
    do {                                                                        \
        unsigned _m = (unsigned)__builtin_amdgcn_update_dpp((int)(x), (int)(x), \
                                                            CTRL, RM, 0xf, false); \
        x = (x < _m) ? x : _m;                                                  \
    } while (0)

// ---------------- FPS: bit-exact farthest point sampling ----------------
// r8 structure (value-only scan, 811 us) + payload-carrying candidate reduce:
// the winning lane carries (idx, x, y, z) through the reduce, so the
// critical-path global centroid load is eliminated entirely.
__global__ __launch_bounds__(1024, 4) void fps_kernel(const float* __restrict__ xyz,
                                                      float* __restrict__ out) {
#pragma clang fp contract(off)
    int b = blockIdx.x;
    int tid = threadIdx.x;
    int lane = tid & 63;
    int w = tid >> 6;  // 16 waves
    const float* base = xyz + (size_t)b * NPTS * 3;
    v2f* yv = (v2f*)dynsmem;       // [8192] y-pairs (64 KB)
    v2f* zv = yv + 8192;           // [8192] z-pairs (64 KB)
    __shared__ unsigned svals[2][16];  // per-wave max value bits, dbuf
    __shared__ float4 sred4[2][16];    // per-wave (idxbits, x, y, z), dbuf
    v2f pxp[8], ddp[8];
#pragma unroll
    for (int jj = 0; jj < 8; ++jj) {
        int p0 = tid + (jj << 11);          // pair: (p0, p0+1024)
        int p1 = p0 + 1024;
        float x0 = base[p0 * 3 + 0], y0 = base[p0 * 3 + 1], z0 = base[p0 * 3 + 2];
        float x1 = base[p1 * 3 + 0], y1 = base[p1 * 3 + 1], z1 = base[p1 * 3 + 2];
        pxp[jj].x = x0; pxp[jj].y = x1;
        v2f yp; yp.x = y0; yp.y = y1;
        v2f zp; zp.x = z0; zp.y = z1;
        yv[(jj << 10) + tid] = yp;
        zv[(jj << 10) + tid] = zp;
        ddp[jj].x = 1e10f; ddp[jj].y = 1e10f;
    }
    // iteration 0: centroid is point 0
    float cx = base[0], cy = base[1], cz = base[2];
    if (tid == 0) {
        float* o = out + (size_t)b * NS * 3;
        o[0] = cx; o[1] = cy; o[2] = cz;
    }
    __syncthreads();
    for (int i = 1; i < NS; ++i) {
        v2f cx2; cx2.x = cx; cx2.y = cx;
        v2f cy2; cy2.x = cy; cy2.y = cy;
        v2f cz2; cz2.x = cz; cz2.y = cz;
        // value-only scan; 4 independent packed max chains
        v2f cm0, cm1, cm2, cm3;
        cm0.x = -1.f; cm0.y = -1.f; cm1 = cm0; cm2 = cm0; cm3 = cm0;
#pragma unroll
        for (int jj = 0; jj < 8; ++jj) {
            v2f yp = yv[(jj << 10) + tid];
            v2f zp = zv[(jj << 10) + tid];
            // bit-exact: contract(off) -> separate rn mul/add, order ((x2+y2)+z2)
            v2f dx = pxp[jj] - cx2;
            v2f dy = yp - cy2;
            v2f dz = zp - cz2;
            v2f d = (dx * dx + dy * dy) + dz * dz;
            v2f nd;
            nd.x = fminf(ddp[jj].x, d.x);
            nd.y = fminf(ddp[jj].y, d.y);
            ddp[jj] = nd;
            if ((jj & 3) == 0) { cm0.x = fmaxf(cm0.x, nd.x); cm0.y = fmaxf(cm0.y, nd.y); }
            if ((jj & 3) == 1) { cm1.x = fmaxf(cm1.x, nd.x); cm1.y = fmaxf(cm1.y, nd.y); }
            if ((jj & 3) == 2) { cm2.x = fmaxf(cm2.x, nd.x); cm2.y = fmaxf(cm2.y, nd.y); }
            if ((jj & 3) == 3) { cm3.x = fmaxf(cm3.x, nd.x); cm3.y = fmaxf(cm3.y, nd.y); }
        }
        v2f m01; m01.x = fmaxf(cm0.x, cm1.x); m01.y = fmaxf(cm0.y, cm1.y);
        v2f m23; m23.x = fmaxf(cm2.x, cm3.x); m23.y = fmaxf(cm2.y, cm3.y);
        float bv = fmaxf(fmaxf(m01.x, m23.x), fmaxf(m01.y, m23.y));  // thread max (exact)
        // wave(64) value max via DPP on u32 bits (positive floats)
        unsigned vb = (unsigned)__float_as_int(bv);
        UMAX_DPP(vb, 0xB1, 0xf);   // quad_perm xor1
        UMAX_DPP(vb, 0x4E, 0xf);   // quad_perm xor2
        UMAX_DPP(vb, 0x141, 0xf);  // row_half_mirror
        UMAX_DPP(vb, 0x140, 0xf);  // row_mirror
        UMAX_DPP(vb, 0x142, 0xa);  // row_bcast15
        UMAX_DPP(vb, 0x143, 0xc);  // row_bcast31
        if (lane == 63) svals[i & 1][w] = vb;
        __syncthreads();           // barrier 1: wave maxes visible
        // block value max: all lanes reduce the 16 slots
        unsigned wv = svals[i & 1][lane & 15];
        UMAX_DPP(wv, 0xB1, 0xf);
        UMAX_DPP(wv, 0x4E, 0xf);
        UMAX_DPP(wv, 0x141, 0xf);
        UMAX_DPP(wv, 0x140, 0xf);
        float W = __int_as_float((int)wv);  // exact block max, uniform
        // candidate wave(s): discover index AND carry payload (x,y,z)
        if (__any(bv == W)) {
            unsigned lidx = 0x7fffffffu;
            float lx = 0.f;
#pragma unroll
            for (int jj = 7; jj >= 0; --jj) {  // descending -> lowest idx wins
                if (ddp[jj].y == W) { lidx = (unsigned)(tid + (jj << 11) + 1024); lx = pxp[jj].y; }
                if (ddp[jj].x == W) { lidx = (unsigned)(tid + (jj << 11));        lx = pxp[jj].x; }
            }
            // own candidate's y/z from LDS (slot 0 garbage for non-matchers)
            unsigned lm = (lidx == 0x7fffffffu) ? 0u : lidx;
            unsigned slot = ((lm >> 11) << 10) + (lm & 1023u);
            unsigned e4 = ((lm >> 10) & 1u) << 2;
            float ly = *(const float*)((const char*)yv + (size_t)slot * 8 + e4);
            float lz = *(const float*)((const char*)zv + (size_t)slot * 8 + e4);
            unsigned widx = lidx;
            UMIN_DPP(widx, 0xB1, 0xf);
            UMIN_DPP(widx, 0x4E, 0xf);
            UMIN_DPP(widx, 0x141, 0xf);
            UMIN_DPP(widx, 0x140, 0xf);
            UMIN_DPP(widx, 0x142, 0xa);
            UMIN_DPP(widx, 0x143, 0xc);
            unsigned wu = (unsigned)__builtin_amdgcn_readlane((int)widx, 63);
            unsigned long long mk = __ballot(lidx == wu);
            int sl = (int)(__ffsll(mk) - 1);
            float sx = __int_as_float(__builtin_amdgcn_readlane(__float_as_int(lx), sl));
            float sy = __int_as_float(__builtin_amdgcn_readlane(__float_as_int(ly), sl));
            float sz = __int_as_float(__builtin_amdgcn_readlane(__float_as_int(lz), sl));
            if (lane == 0) sred4[i & 1][w] = make_float4(__int_as_float((int)wu), sx, sy, sz);
        } else {
            if (lane == 0) sred4[i & 1][w] = make_float4(__int_as_float(0x7fffffff), 0.f, 0.f, 0.f);
        }
        __syncthreads();           // barrier 2: candidate payloads visible
        float4 s4 = sred4[i & 1][lane & 15];
        unsigned ci = (unsigned)__float_as_int(s4.x);
        UMIN_DPP(ci, 0xB1, 0xf);
        UMIN_DPP(ci, 0x4E, 0xf);
        UMIN_DPP(ci, 0x141, 0xf);
        UMIN_DPP(ci, 0x140, 0xf);
        unsigned long long mk2 = __ballot((unsigned)__float_as_int(s4.x) == ci);
        int sl2 = (int)(__ffsll(mk2) - 1);
        cx = __int_as_float(__builtin_amdgcn_readlane(__float_as_int(s4.y), sl2));
        cy = __int_as_float(__builtin_amdgcn_readlane(__float_as_int(s4.z), sl2));
        cz = __int_as_float(__builtin_amdgcn_readlane(__float_as_int(s4.w), sl2));
        if (tid == 0) {
            float* o = out + ((size_t)b * NS + i) * 3;
            o[0] = cx; o[1] = cy; o[2] = cz;
        }
    }
}

// ------------- Ball query (exact expanded-form distance) + gather -------------
__global__ __launch_bounds__(256) void ballq_kernel(const float* __restrict__ xyz,
                                                    const float* __restrict__ pts,
                                                    const float* __restrict__ newxyz,
                                                    float* __restrict__ feat) {
    int w = threadIdx.x >> 6;
    int lane = threadIdx.x & 63;
    int wid = blockIdx.x * 4 + w;   // 0..4095 == b*512+s
    int b = wid >> 9;
    const float* nx = newxyz + (size_t)wid * 3;
    float cx = nx[0], cy = nx[1], cz = nx[2];
    float sa = __fadd_rn(__fadd_rn(__fmul_rn(cx, cx), __fmul_rn(cy, cy)),
                         __fmul_rn(cz, cz));
    __shared__ int sidx[4][64];
    const float* base = xyz + (size_t)b * NPTS * 3;
    int cnt = 0;
    for (int off = 0; off < NPTS && cnt < NK; off += 64) {
        int p = off + lane;
        float bx = base[p * 3 + 0], by = base[p * 3 + 1], bz = base[p * 3 + 2];
        float sb = __fadd_rn(__fadd_rn(__fmul_rn(bx, bx), __fmul_rn(by, by)),
                             __fmul_rn(bz, bz));
        float dt = __fadd_rn(__fadd_rn(__fmul_rn(cx, bx), __fmul_rn(cy, by)),
                             __fmul_rn(cz, bz));
        float sq = __fsub_rn(__fadd_rn(sa, sb), __fmul_rn(2.0f, dt));
        bool inb = !(sq > RAD2);           // strict >, matches reference
        unsigned long long mask = __ballot(inb);
        int pos = cnt + (int)__popcll(mask & ((1ull << lane) - 1ull));
        if (inb && pos < NK) sidx[w][pos] = p;
        cnt += (int)__popcll(mask);
    }
    __syncthreads();
    int filled = cnt < NK ? cnt : NK;
    int sel = (lane < filled) ? lane : 0;
    int p = (filled > 0) ? sidx[w][sel] : 0;  // filled>0 always (self in radius)
    float gx = base[p * 3 + 0], gy = base[p * 3 + 1], gz = base[p * 3 + 2];
    const float* pb = pts + (size_t)b * NPTS * 3;
    float q0 = pb[p * 3 + 0], q1 = pb[p * 3 + 1], q2 = pb[p * 3 + 2];
    float* fr = feat + ((size_t)wid * NK + lane) * 6;
    fr[0] = __fsub_rn(gx, cx);
    fr[1] = __fsub_rn(gy, cy);
    fr[2] = __fsub_rn(gz, cz);
    fr[3] = q0; fr[4] = q1; fr[5] = q2;
}

// ---------------- Layer-0 stats: per-channel sum/sumsq of h0raw ----------------
__global__ __launch_bounds__(256) void stats0_kernel(const float* __restrict__ feat,
                                                     const float* __restrict__ W0,
                                                     const float* __restrict__ b0,
                                                     float* __restrict__ stats) {
    int lane = threadIdx.x & 63;
    int wid = blockIdx.x * 4 + (threadIdx.x >> 6);  // 0..1023
    float w0[6];
#pragma unroll
    for (int j = 0; j < 6; ++j) w0[j] = W0[lane * 6 + j];
    float bb = b0[lane];
    float ssum = 0.f, ssq = 0.f;
    int r0 = wid * 256;
    for (int r = r0; r < r0 + 256; ++r) {
        const float* f = feat + (size_t)r * 6;
        float h = bb;
#pragma unroll
        for (int j = 0; j < 6; ++j) h = fmaf(w0[j], f[j], h);
        ssum += h;
        ssq = fmaf(h, h, ssq);
    }
    atomicAdd(&stats[lane], ssum);
    atomicAdd(&stats[64 + lane], ssq);
}

__global__ void fin0_kernel(const float* __restrict__ g0, const float* __restrict__ be0,
                            float* __restrict__ stats) {
    int c = threadIdx.x;  // 64 threads
    const float inv = 1.0f / (float)MTOT;  // 2^-18, exact
    float mu = stats[c] * inv;
    float var = fmaxf(stats[64 + c] * inv - mu * mu, 0.f);
    float a = g0[c] * rsqrtf(var + 1e-5f);
    stats[384 + c] = a;
    stats[448 + c] = fmaf(-mu, a, be0[c]);
}

// ---------------- Layer-1 stats: recompute h0n -> h1raw, sum/sumsq ----------------
__global__ __launch_bounds__(256) void stats1_kernel(const float* __restrict__ feat,
                                                     const float* __restrict__ W0,
                                                     const float* __restrict__ b0,
                                                     const float* __restrict__ W1,
                                                     const float* __restrict__ b1,
                                                     float* __restrict__ stats) {
    int lane = threadIdx.x & 63;
    int w = threadIdx.x >> 6;
    int half = w & 1;
    int pairG = blockIdx.x * 2 + (w >> 1);  // 0..2047
    int ch = half * 64 + lane;
    float w0r[6];
#pragma unroll
    for (int j = 0; j < 6; ++j) w0r[j] = W0[lane * 6 + j];
    float b0v = b0[lane];
    float a0 = stats[384 + lane], c0 = stats[448 + lane];
    float w1r[64];
#pragma unroll
    for (int j = 0; j < 64; ++j) w1r[j] = W1[ch * 64 + j];
    float b1v = b1[ch];
    float ssum = 0.f, ssq = 0.f;
    int r0 = pairG * 128;
    for (int r = r0; r < r0 + 128; ++r) {
        const float* f = feat + (size_t)r * 6;
        float h = b0v;
#pragma unroll
        for (int j = 0; j < 6; ++j) h = fmaf(w0r[j], f[j], h);
        float h0n = fmaxf(fmaf(a0, h, c0), 0.f);
        int hbits = __float_as_int(h0n);
        float a0c = 0.f, a1c = 0.f, a2c = 0.f, a3c = 0.f;
#pragma unroll
        for (int j = 0; j < 64; j += 4) {
            a0c = fmaf(w1r[j + 0], __int_as_float(__builtin_amdgcn_readlane(hbits, j + 0)), a0c);
            a1c = fmaf(w1r[j + 1], __int_as_float(__builtin_amdgcn_readlane(hbits, j + 1)), a1c);
            a2c = fmaf(w1r[j + 2], __int_as_float(__builtin_amdgcn_readlane(hbits, j + 2)), a2c);
            a3c = fmaf(w1r[j + 3], __int_as_float(__builtin_amdgcn_readlane(hbits, j + 3)), a3c);
        }
        float acc = b1v + ((a0c + a1c) + (a2c + a3c));
        ssum += acc;
        ssq = fmaf(acc, acc, ssq);
    }
    atomicAdd(&stats[128 + ch], ssum);
    atomicAdd(&stats[256 + ch], ssq);
}

__global__ void fin1_kernel(const float* __restrict__ g1, const float* __restrict__ be1,
                            float* __restrict__ stats) {
    int c = threadIdx.x;  // 128 threads
    const float inv = 1.0f / (float)MTOT;
    float mu = stats[128 + c] * inv;
    float var = fmaxf(stats[256 + c] * inv - mu * mu, 0.f);
    float a = g1[c] * rsqrtf(var + 1e-5f);
    stats[512 + c] = a;
    stats[640 + c] = fmaf(-mu, a, be1[c]);
}

// ---------------- Final: MFMA bf16-split GEMM + BN + maxpool ----------------
// Per group (64 rows x 64 ch): h0n recomputed exactly (same expression as
// stats1), split hi/lo bf16 into LDS (XOR-swizzled); W1 split staged once per
// block. H1 = X*W1^T via mfma_f32_16x16x32_bf16 (hi*hi + hi*lo + lo*hi,
// ~fp32 accuracy). Epilogue: BN1 + relu + max over 64 rows, store.
__global__ __launch_bounds__(256) void final_mfma_kernel(const float* __restrict__ feat,
                                                         const float* __restrict__ W0,
                                                         const float* __restrict__ b0,
                                                         const float* __restrict__ W1,
                                                         const float* __restrict__ b1,
                                                         const float* __restrict__ stats,
                                                         float* __restrict__ out) {
    char* lds = dynsmem;
    // [0,16K) W1hi [128][64] bf16 swz | [16K,32K) W1lo | [32K+w*16K) X: hi 8K, lo 8K
    int tid = threadIdx.x;
    int lane = tid & 63;
    int w = tid >> 6;
    int g = blockIdx.x * 4 + w;  // 0..4095
    // --- stage W1 hi/lo (whole block) ---
    for (int idx = tid; idx < 8192; idx += 256) {
        int o = idx >> 6, c = idx & 63;
        float v = W1[idx];
        unsigned u = __float_as_uint(v);
        unsigned hi = (u + 0x7fffu + ((u >> 16) & 1u)) >> 16;
        float rem = v - __uint_as_float(hi << 16);
        unsigned ur = __float_as_uint(rem);
        unsigned lo = (ur + 0x7fffu + ((ur >> 16) & 1u)) >> 16;
        int byt = (c * 2) ^ ((o & 7) << 4);
        *(unsigned short*)(lds + o * 128 + byt) = (unsigned short)hi;
        *(unsigned short*)(lds + 16384 + o * 128 + byt) = (unsigned short)lo;
    }
    // --- phase 1: h0n (exact, same expression as stats1) -> split into LDS ---
    char* X = lds + 32768 + w * 16384;  // hi @0, lo @8192
    float w0r[6];
#pragma unroll
    for (int j = 0; j < 6; ++j) w0r[j] = W0[lane * 6 + j];
    float b0v = b0[lane];
    float a0 = stats[384 + lane], c0v = stats[448 + lane];
    __syncthreads();  // W1 staged
    const float* fb = feat + (size_t)g * 64 * 6;
#pragma unroll 4
    for (int r = 0; r < 64; ++r) {
        const float* f = fb + r * 6;
        float h = b0v;
#pragma unroll
        for (int j = 0; j < 6; ++j) h = fmaf(w0r[j], f[j], h);
        float hn = fmaxf(fmaf(a0, h, c0v), 0.f);
        unsigned u = __float_as_uint(hn);
        unsigned hi = (u + 0x7fffu + ((u >> 16) & 1u)) >> 16;
        float rem = hn - __uint_as_float(hi << 16);
        unsigned ur = __float_as_uint(rem);
        unsigned lo = (ur + 0x7fffu + ((ur >> 16) & 1u)) >> 16;
        int byt = (lane * 2) ^ ((r & 7) << 4);
        *(unsigned short*)(X + r * 128 + byt) = (unsigned short)hi;
        *(unsigned short*)(X + 8192 + r * 128 + byt) = (unsigned short)lo;
    }
    __syncthreads();  // X + W1 visible
    // --- BN1 params per tn tile (o = tn*16 + lane&15) ---
    float a1v[8], d1v[8];
#pragma unroll
    for (int tn = 0; tn < 8; ++tn) {
        int o = tn * 16 + (lane & 15);
        float a1 = stats[512 + o];
        a1v[tn] = a1;
        d1v[tn] = fmaf(a1, b1[o], stats[640 + o]);  // a1*b1 + c1
    }
    float mx[8];
#pragma unroll
    for (int tn = 0; tn < 8; ++tn) mx[tn] = -1e30f;
    // --- GEMM: tm outer (A loaded once), tn inner (B loaded in-loop) ---
#pragma unroll
    for (int tm = 0; tm < 4; ++tm) {
        bfv8 Ah[2], Al[2];
#pragma unroll
        for (int tk = 0; tk < 2; ++tk) {
            int r = tm * 16 + (lane & 15);
            int colb = (((lane >> 4) * 16) + tk * 64) ^ ((r & 7) << 4);
            Ah[tk] = *(const bfv8*)(X + r * 128 + colb);
            Al[tk] = *(const bfv8*)(X + 8192 + r * 128 + colb);
        }
#pragma unroll
        for (int tn = 0; tn < 8; ++tn) {
            int o = tn * 16 + (lane & 15);
            f32x4 acc = {0.f, 0.f, 0.f, 0.f};
#pragma unroll
            for (int tk = 0; tk < 2; ++tk) {
                int colb = (((lane >> 4) * 16) + tk * 64) ^ ((o & 7) << 4);
                bfv8 Bh = *(const bfv8*)(lds + o * 128 + colb);
                bfv8 Bl = *(const bfv8*)(lds + 16384 + o * 128 + colb);
                acc = __builtin_amdgcn_mfma_f32_16x16x32_bf16(Ah[tk], Bh, acc, 0, 0, 0);
                acc = __builtin_amdgcn_mfma_f32_16x16x32_bf16(Ah[tk], Bl, acc, 0, 0, 0);
                acc = __builtin_amdgcn_mfma_f32_16x16x32_bf16(Al[tk], Bh, acc, 0, 0, 0);
            }
            // epilogue: h1n = relu(a1*acc + (a1*b1 + c1)); max over the 4 rows
            float t0 = fmaxf(fmaf(a1v[tn], acc[0], d1v[tn]), 0.f);
            float t1 = fmaxf(fmaf(a1v[tn], acc[1], d1v[tn]), 0.f);
            float t2 = fmaxf(fmaf(a1v[tn], acc[2], d1v[tn]), 0.f);
            float t3 = fmaxf(fmaf(a1v[tn], acc[3], d1v[tn]), 0.f);
            mx[tn] = fmaxf(mx[tn], fmaxf(fmaxf(t0, t1), fmaxf(t2, t3)));
        }
    }
    // cross-lane max over row groups (lanes 16 apart hold other rows)
#pragma unroll
    for (int tn = 0; tn < 8; ++tn) {
        float v = mx[tn];
        v = fmaxf(v, __shfl_xor(v, 16));
        v = fmaxf(v, __shfl_xor(v, 32));
        mx[tn] = v;
    }
    if (lane < 16) {
        size_t ob = 12288 + (size_t)g * 128;
#pragma unroll
        for (int tn = 0; tn < 8; ++tn) out[ob + tn * 16 + lane] = mx[tn];
    }
}

extern "C" void kernel_launch(void* const* d_in, const int* in_sizes, int n_in,
                              void* d_out, int out_size, void* d_ws, size_t ws_size,
                              hipStream_t stream) {
    const float* xyz = (const float*)d_in[0];
    const float* pts = (const float*)d_in[1];
    const float* W0  = (const float*)d_in[2];
    const float* b0  = (const float*)d_in[3];
    const float* g0  = (const float*)d_in[4];
    const float* be0 = (const float*)d_in[5];
    const float* W1  = (const float*)d_in[6];
    const float* b1  = (const float*)d_in[7];
    const float* g1  = (const float*)d_in[8];
    const float* be1 = (const float*)d_in[9];
    float* out = (float*)d_out;

    float* feat  = (float*)d_ws;                     // 262144*6 floats = 6.29 MB
    float* stats = feat + (size_t)MTOT * 6;          // 768 floats

    // opt-in to large dynamic LDS (idempotent, host-side, capture-safe)
    const int fps_lds = 2 * NPTS * (int)sizeof(float);  // 131072
    (void)hipFuncSetAttribute(reinterpret_cast<const void*>(fps_kernel),
                              hipFuncAttributeMaxDynamicSharedMemorySize, fps_lds);
    const int fm_lds = 98304;  // 32K W1 + 4x16K X
    (void)hipFuncSetAttribute(reinterpret_cast<const void*>(final_mfma_kernel),
                              hipFuncAttributeMaxDynamicSharedMemorySize, fm_lds);

    (void)hipMemsetAsync(stats, 0, 384 * sizeof(float), stream);
    fps_kernel<<<NB, 1024, fps_lds, stream>>>(xyz, out);
    ballq_kernel<<<1024, 256, 0, stream>>>(xyz, pts, out, feat);
    stats0_kernel<<<256, 256, 0, stream>>>(feat, W0, b0, stats);
    fin0_kernel<<<1, 64, 0, stream>>>(g0, be0, stats);
    stats1_kernel<<<1024, 256, 0, stream>>>(feat, W0, b0, W1, b1, stats);
    fin1_kernel<<<1, 128, 0, stream>>>(g1, be1, stats);
    final_mfma_kernel<<<1024, 256, fm_lds, stream>>>(feat, W0, b0, W1, b1, stats, out);
}